// Round 4
// baseline (259.669 us; speedup 1.0000x reference)
//
#include <hip/hip_runtime.h>

// CompanionSSM, 3-kernel transpose sandwich (needs 64 MiB workspace):
//  K1 transpose_in : u[4][4096][1024] -> u_t[64 hg][4 b][4096 l][16 ch] (ws)
//                    LDS-tiled 64x256, both sides 1KB-contiguous per instr.
//  K2 fused<true>  : proven round-3 companion kernel, but each block reads a
//                    fully contiguous 256KB stream (u_t) and writes Y in-place
//                    over it (same rows read by the same wave -> race-free).
//  K3 transpose_out: y_t (ws) -> out, mirror of K1.
// Rationale: rounds 0-3 all pinned at ~1.2 TB/s effective = the 64B-granular
// 4KB-stride DRAM pattern ceiling. Sandwich makes every access streaming.
// Fallback (ws too small): fused<false> = exact round-3 behavior.

#define NKH 256
#define KD  64
#define SL  4096
#define DM  1024

typedef __attribute__((ext_vector_type(8))) short short8;
typedef __attribute__((ext_vector_type(4))) float floatx4;

#define VOFF      0
#define WOFF      32768
#define KOFF      65536
#define SLOTS_OFF 98304
#define PHI_OFF   131072
#define KV_OFF    133120
#define LDS_TOTAL 134144

static __device__ __forceinline__ unsigned pack_bf16(float a, float b) {
  union { float f; unsigned u; } ua, ub;
  ua.f = a; ub.f = b;
  return __builtin_amdgcn_perm(ub.u + 0x8000u, ua.u + 0x8000u, 0x07060302u);
}
static __device__ __forceinline__ unsigned short f2bfru(float x) {
  union { float f; unsigned u; } v; v.f = x;
  return (unsigned short)((v.u + 0x8000u) >> 16);
}
static __device__ __forceinline__ float bflo(unsigned d) {
  union { unsigned u; float f; } v; v.u = d << 16; return v.f;
}
static __device__ __forceinline__ float bfhi(unsigned d) {
  union { unsigned u; float f; } v; v.u = d & 0xffff0000u; return v.f;
}
static __device__ __forceinline__ float wredsum(float x) {
#pragma unroll
  for (int off = 32; off; off >>= 1) x += __shfl_xor(x, off, 64);
  return x;
}
// 4x4 transpose across a DPP quad (lanes 4k..4k+3, c = lane&3).
static __device__ __forceinline__ float4 qtr(float4 v, int c) {
  const bool c1 = (c & 1) != 0, c2 = (c & 2) != 0;
  float a01 = __shfl_xor(v.y, 1, 64), a10 = __shfl_xor(v.x, 1, 64);
  float a23 = __shfl_xor(v.w, 1, 64), a32 = __shfl_xor(v.z, 1, 64);
  float t0 = c1 ? a01 : v.x, t1 = c1 ? v.y : a10;
  float t2 = c1 ? a23 : v.z, t3 = c1 ? v.w : a32;
  float b02 = __shfl_xor(t2, 2, 64), b20 = __shfl_xor(t0, 2, 64);
  float b13 = __shfl_xor(t3, 2, 64), b31 = __shfl_xor(t1, 2, 64);
  float4 r;
  r.x = c2 ? b02 : t0; r.y = c2 ? b13 : t1;
  r.z = c2 ? t2 : b20; r.w = c2 ? t3 : b31;
  return r;
}
// per-lane 4-way select (column ch uses head ch>>2)
static __device__ __forceinline__ floatx4 sel4(floatx4 a, floatx4 b,
                                               floatx4 c, floatx4 d, int hs) {
  floatx4 r;
#pragma unroll
  for (int k = 0; k < 4; ++k) {
    const float x = (hs & 1) ? b[k] : a[k];
    const float y = (hs & 1) ? d[k] : c[k];
    r[k] = (hs & 2) ? y : x;
  }
  return r;
}
// frag-major 16B-group byte offset for 64x64 bf16: element (row, colg..colg+7)
static __device__ __forceinline__ int fmoff(int row, int colg) {
  return ((((row >> 4) * 2 + (colg >> 5)) * 64 + ((colg >> 3) & 3) * 16 + (row & 15)) << 4);
}

// ================= K1: u -> u_t (ws) ====================================
__global__ __launch_bounds__(256) void transpose_in(
    const float* __restrict__ u, float* __restrict__ ut)
{
  __shared__ float tile[64 * 260];
  const int bid = blockIdx.x;
  const int bq = bid & 3, lt = (bid >> 2) & 63, dt = bid >> 8;
  const int l0 = lt * 64, d0 = dt * 256;
  const int t = threadIdx.x, w = t >> 6, lane = t & 63;
#pragma unroll
  for (int rr = 0; rr < 16; ++rr) {
    const int row = w * 16 + rr;
    const float4 v = *(const float4*)(u + ((size_t)(bq * SL + l0 + row) * DM + d0 + lane * 4));
    *(float4*)(tile + row * 260 + lane * 4) = v;
  }
  __syncthreads();
  const int q = lane >> 2, c4 = (lane & 3) * 4;
#pragma unroll
  for (int p = 0; p < 4; ++p) {
    const int c = w * 4 + p;
    const int hg = dt * 16 + c;
    float* dst = ut + ((size_t)(hg * 4 + bq) * SL + l0) * 16;
#pragma unroll
    for (int ii = 0; ii < 4; ++ii) {
      const int l = ii * 16 + q;
      *(float4*)(dst + l * 16 + c4) = *(const float4*)(tile + l * 260 + c * 16 + c4);
    }
  }
}

// ================= K3: y_t (ws) -> out ==================================
__global__ __launch_bounds__(256) void transpose_out(
    const float* __restrict__ yt, float* __restrict__ out)
{
  __shared__ float tile[64 * 260];
  const int bid = blockIdx.x;
  const int bq = bid & 3, lt = (bid >> 2) & 63, dt = bid >> 8;
  const int l0 = lt * 64, d0 = dt * 256;
  const int t = threadIdx.x, w = t >> 6, lane = t & 63;
  const int q = lane >> 2, c4 = (lane & 3) * 4;
#pragma unroll
  for (int p = 0; p < 4; ++p) {
    const int c = w * 4 + p;
    const int hg = dt * 16 + c;
    const float* src = yt + ((size_t)(hg * 4 + bq) * SL + l0) * 16;
#pragma unroll
    for (int ii = 0; ii < 4; ++ii) {
      const int l = ii * 16 + q;
      *(float4*)(tile + l * 260 + c * 16 + c4) = *(const float4*)(src + l * 16 + c4);
    }
  }
  __syncthreads();
#pragma unroll
  for (int rr = 0; rr < 16; ++rr) {
    const int row = w * 16 + rr;
    *(float4*)(out + ((size_t)(bq * SL + l0 + row) * DM + d0 + lane * 4)) =
        *(const float4*)(tile + row * 260 + lane * 4);
  }
}

// ================= K2: companion (round-3 proven schedule) ==============
// LINEAR=1: uin/uout = ws (u_t layout, in-place), row stride 16.
// LINEAR=0: uin=u, uout=out (original layout), row stride 1024.
template <bool LINEAR>
__global__ __launch_bounds__(512, 1) void fused_kernel(
    const float* __restrict__ uin, const float* __restrict__ ga,
    const float* __restrict__ gb, const float* __restrict__ gc,
    float* __restrict__ uout)
{
  __shared__ __align__(16) char lds[LDS_TOTAL];
  float* phi = (float*)(lds + PHI_OFF);   // f32[4][128]
  float* kv  = (float*)(lds + KV_OFF);    // f32[4][64]

  const int i = blockIdx.x;
  const int hg = i >> 2, bq = i & 3;      // head-group, batch
  const int t = threadIdx.x;
  const int w = t >> 6, lane = t & 63;
  const int n16 = lane & 15, quad = lane >> 4;
  const int cq = n16 >> 2, cj = n16 & 3;  // channel-quarter (= head), sub-ch

  // ---------------- prep chains: wave w -> head w>>1, role w&1 -------------
  {
    const int hw = w >> 1, role = w & 1;
    const int gh = 4 * hg + hw;
    const float av = ga[gh * KD + lane];
    const float an = av / wredsum(fabsf(av));   // mean(|rowsum|) >> eps
    const float cv = gc[gh * KD + lane];
    if (role) {
      phi[hw * 128 + lane] = cv;                // phi_p = c_p for p<64
      float g = an;                             // g_64 = A^64 e0 = a_n
      union { short8 v; unsigned short us[8]; } g8;
      for (int p = 64; p < 128; ++p) {
        g8.us[p & 7] = f2bfru(g);               // T col (p-64), row = lane
        if ((p & 7) == 7)
          *(short8*)(lds + SLOTS_OFF + hw * 8192 + fmoff(lane, (p - 64) & ~7)) = g8.v;
        const float d = wredsum(cv * g);
        if (lane == 0) phi[hw * 128 + p] = d;
        const float top = __shfl(g, 63, 64);
        const float gm1 = __shfl_up(g, 1, 64);
        g = (lane > 0 ? gm1 : 0.0f) + an * top;
      }
    } else {
      float v = gb[gh * KD + lane];             // v_j = A^j b
      union { short8 v8; unsigned short us[8]; } v8u;
      for (int j = 0; j < KD; ++j) {
        const float d = wredsum(cv * v);
        if (lane == 0) kv[hw * 64 + j] = d;     // k[j] = c.v_j
        const int col = 63 - j;                 // V col m = v_{63-m}
        v8u.us[col & 7] = f2bfru(v);
        if ((col & 7) == 0)
          *(short8*)(lds + VOFF + hw * 8192 + fmoff(lane, col)) = v8u.v8;
        const float top = __shfl(v, 63, 64);
        const float vm1 = __shfl_up(v, 1, 64);
        v = (lane > 0 ? vm1 : 0.0f) + an * top;
      }
    }
  }
  __syncthreads();

  // ---------------- W/K frag fills + T-frag extraction ----------------
  for (int idx = t; idx < 2048; idx += 512) {
    const int h = idx >> 9, g2 = idx & 511;
    const int cgi = g2 >> 6, row = g2 & 63;
    const int colg = cgi * 8;
    union { short8 v; unsigned short us[8]; } wb, kb;
#pragma unroll
    for (int jj = 0; jj < 8; ++jj) {
      wb.us[jj] = f2bfru(phi[h * 128 + row + 1 + colg + jj]);
      const int m = colg + jj;
      kb.us[jj] = (m <= row) ? f2bfru(kv[h * 64 + row - m]) : (unsigned short)0;
    }
    *(short8*)(lds + WOFF + h * 8192 + fmoff(row, colg)) = wb.v;
    *(short8*)(lds + KOFF + h * 8192 + fmoff(row, colg)) = kb.v;
  }
  short8 At[4][4][2];
#pragma unroll
  for (int h = 0; h < 4; ++h)
#pragma unroll
    for (int rt = 0; rt < 4; ++rt)
#pragma unroll
      for (int kt = 0; kt < 2; ++kt)
        At[h][rt][kt] = *(const short8*)(lds + SLOTS_OFF + h * 8192 +
                                         (((rt * 2 + kt) * 64 + lane) << 4));
  __syncthreads();   // T temp dead -> slots usable

  // ---------------- main: 4 quarters x 16 chunks ----------------
  const size_t RS = LINEAR ? 16 : DM;     // row stride (f32)
  const float* ubase = LINEAR
      ? uin + ((size_t)(hg * 4 + bq) * SL) * 16 + cq * 4
      : uin + (size_t)bq * ((size_t)SL * DM) + hg * 16 + cq * 4;
  float* obase = LINEAR
      ? uout + ((size_t)(hg * 4 + bq) * SL) * 16 + cq * 4
      : uout + (size_t)bq * ((size_t)SL * DM) + hg * 16 + cq * 4;
  const int srcA = n16 + 16 * ((2 * quad) & 3);
  const int srcB = n16 + 16 * ((2 * quad + 1) & 3);
  const bool hi = (quad >= 2);
  const short8 Z8 = {0, 0, 0, 0, 0, 0, 0, 0};
  short8 B0 = Z8, B1 = Z8;                // scan carry (wave 0)

#pragma unroll 1
  for (int Q = 0; Q < 4; ++Q) {
    const int q0 = Q * 16;
    short8 UB[2][2];

    // ---- Phase A: 2 chunks/wave; contiguous float4 loads + qtr transpose ----
    {
      float4 L[2][2][2];   // [s][kt][hf]
#pragma unroll
      for (int s = 0; s < 2; ++s) {
        const int qg = q0 + w + 8 * s;
#pragma unroll
        for (int kt = 0; kt < 2; ++kt)
#pragma unroll
          for (int hf = 0; hf < 2; ++hf)
            L[s][kt][hf] = *(const float4*)(ubase +
                (size_t)(qg * 64 + 32 * kt + 8 * quad + 4 * hf + cj) * RS);
      }
#pragma unroll
      for (int s = 0; s < 2; ++s) {
        const int lq = w + 8 * s;
#pragma unroll
        for (int kt = 0; kt < 2; ++kt) {
          float4 W0 = qtr(L[s][kt][0], cj);
          float4 W1 = qtr(L[s][kt][1], cj);
          union { short8 v; unsigned uu[4]; } ub;
          ub.uu[0] = pack_bf16(W0.x, W0.y); ub.uu[1] = pack_bf16(W0.z, W0.w);
          ub.uu[2] = pack_bf16(W1.x, W1.y); ub.uu[3] = pack_bf16(W1.z, W1.w);
          UB[s][kt] = ub.v;
        }
        char* slot = lds + SLOTS_OFF + lq * 2048;
#pragma unroll
        for (int rt = 0; rt < 4; ++rt) {
          floatx4 rh[4];
#pragma unroll
          for (int h = 0; h < 4; ++h) {
            const short8 v0 = *(const short8*)(lds + VOFF + h * 8192 + (((rt * 2 + 0) * 64 + lane) << 4));
            const short8 v1 = *(const short8*)(lds + VOFF + h * 8192 + (((rt * 2 + 1) * 64 + lane) << 4));
            floatx4 acc = {0.f, 0.f, 0.f, 0.f};
            acc   = __builtin_amdgcn_mfma_f32_16x16x32_bf16(v0, UB[s][0], acc, 0, 0, 0);
            rh[h] = __builtin_amdgcn_mfma_f32_16x16x32_bf16(v1, UB[s][1], acc, 0, 0, 0);
          }
          floatx4 r = sel4(rh[0], rh[1], rh[2], rh[3], cq);
          uint2 pk; pk.x = pack_bf16(r[0], r[1]); pk.y = pack_bf16(r[2], r[3]);
          *(uint2*)(slot + rt * 512 + lane * 8) = pk;
        }
      }
    }
    __syncthreads();

    // ---- Phase B: wave 0 serial scan; slots <- entering S ----
    if (w == 0) {
#pragma unroll 1
      for (int lq = 0; lq < 16; ++lq) {
        char* sp = lds + SLOTS_OFF + lq * 2048;
        uint2 rb[4];
#pragma unroll
        for (int rt = 0; rt < 4; ++rt) rb[rt] = *(const uint2*)(sp + rt * 512 + lane * 8);
        asm volatile("" ::: "memory");
        *(short8*)(sp + lane * 16)        = B0;
        *(short8*)(sp + 1024 + lane * 16) = B1;
        unsigned pk[4][2];
#pragma unroll
        for (int rt = 0; rt < 4; ++rt) {
          floatx4 cs;
          cs[0] = bflo(rb[rt].x); cs[1] = bfhi(rb[rt].x);
          cs[2] = bflo(rb[rt].y); cs[3] = bfhi(rb[rt].y);
          floatx4 ah[4];
#pragma unroll
          for (int h = 0; h < 4; ++h) {
            floatx4 a0 = __builtin_amdgcn_mfma_f32_16x16x32_bf16(At[h][rt][0], B0, cs, 0, 0, 0);
            ah[h]      = __builtin_amdgcn_mfma_f32_16x16x32_bf16(At[h][rt][1], B1, a0, 0, 0, 0);
          }
          floatx4 acc = sel4(ah[0], ah[1], ah[2], ah[3], cq);
          pk[rt][0] = pack_bf16(acc[0], acc[1]);
          pk[rt][1] = pack_bf16(acc[2], acc[3]);
        }
        union { short8 v; unsigned uu[4]; } nb0, nb1;
        unsigned xa, xb;
        xa = __shfl(pk[0][0], srcA, 64); xb = __shfl(pk[1][0], srcA, 64); nb0.uu[0] = hi ? xb : xa;
        xa = __shfl(pk[0][1], srcA, 64); xb = __shfl(pk[1][1], srcA, 64); nb0.uu[1] = hi ? xb : xa;
        xa = __shfl(pk[0][0], srcB, 64); xb = __shfl(pk[1][0], srcB, 64); nb0.uu[2] = hi ? xb : xa;
        xa = __shfl(pk[0][1], srcB, 64); xb = __shfl(pk[1][1], srcB, 64); nb0.uu[3] = hi ? xb : xa;
        xa = __shfl(pk[2][0], srcA, 64); xb = __shfl(pk[3][0], srcA, 64); nb1.uu[0] = hi ? xb : xa;
        xa = __shfl(pk[2][1], srcA, 64); xb = __shfl(pk[3][1], srcA, 64); nb1.uu[1] = hi ? xb : xa;
        xa = __shfl(pk[2][0], srcB, 64); xb = __shfl(pk[3][0], srcB, 64); nb1.uu[2] = hi ? xb : xa;
        xa = __shfl(pk[2][1], srcB, 64); xb = __shfl(pk[3][1], srcB, 64); nb1.uu[3] = hi ? xb : xa;
        B0 = nb0.v; B1 = nb1.v;
      }
    }
    __syncthreads();

    // ---- Phase C: Y = Toep@U + W@S; qtr transpose; contiguous stores ----
#pragma unroll
    for (int s = 0; s < 2; ++s) {
      const int lq = w + 8 * s;
      const int qg = q0 + lq;
      char* sp = lds + SLOTS_OFF + lq * 2048;
      const short8 S0 = *(const short8*)(sp + lane * 16);
      const short8 S1 = *(const short8*)(sp + 1024 + lane * 16);
#pragma unroll
      for (int rt = 0; rt < 4; ++rt) {
        floatx4 th[4];
#pragma unroll
        for (int h = 0; h < 4; ++h) {
          const short8 k0 = *(const short8*)(lds + KOFF + h * 8192 + (((rt * 2 + 0) * 64 + lane) << 4));
          const short8 k1 = *(const short8*)(lds + KOFF + h * 8192 + (((rt * 2 + 1) * 64 + lane) << 4));
          const short8 w0 = *(const short8*)(lds + WOFF + h * 8192 + (((rt * 2 + 0) * 64 + lane) << 4));
          const short8 w1 = *(const short8*)(lds + WOFF + h * 8192 + (((rt * 2 + 1) * 64 + lane) << 4));
          floatx4 ty = {0.f, 0.f, 0.f, 0.f};
          ty    = __builtin_amdgcn_mfma_f32_16x16x32_bf16(k0, UB[s][0], ty, 0, 0, 0);
          ty    = __builtin_amdgcn_mfma_f32_16x16x32_bf16(k1, UB[s][1], ty, 0, 0, 0);
          ty    = __builtin_amdgcn_mfma_f32_16x16x32_bf16(w0, S0,       ty, 0, 0, 0);
          th[h] = __builtin_amdgcn_mfma_f32_16x16x32_bf16(w1, S1,       ty, 0, 0, 0);
        }
        floatx4 ty = sel4(th[0], th[1], th[2], th[3], cq);
        float4 yv; yv.x = ty[0]; yv.y = ty[1]; yv.z = ty[2]; yv.w = ty[3];
        float4 tw = qtr(yv, cj);
        *(float4*)(obase + (size_t)(qg * 64 + 16 * rt + 4 * quad + cj) * RS) = tw;
      }
    }
    // no barrier: next Phase A touches only this wave's own slots, and
    // Phase B(Q+1) is ordered by the post-A barrier.
  }
}

template __global__ void fused_kernel<true>(const float*, const float*,
                                            const float*, const float*, float*);
template __global__ void fused_kernel<false>(const float*, const float*,
                                             const float*, const float*, float*);

// ---------------------------------------------------------------- launch --
extern "C" void kernel_launch(void* const* d_in, const int* in_sizes, int n_in,
                              void* d_out, int out_size, void* d_ws, size_t ws_size,
                              hipStream_t stream)
{
  const float* u = (const float*)d_in[0];
  const float* a = (const float*)d_in[1];
  const float* b = (const float*)d_in[2];
  const float* c = (const float*)d_in[3];
  float* out = (float*)d_out;
  (void)in_sizes; (void)n_in; (void)out_size;

  const size_t WS_NEED = (size_t)4 * SL * DM * sizeof(float);  // 64 MiB
  if (d_ws != nullptr && ws_size >= WS_NEED) {
    float* ut = (float*)d_ws;
    transpose_in<<<1024, 256, 0, stream>>>(u, ut);
    fused_kernel<true><<<NKH, 512, 0, stream>>>(ut, a, b, c, ut);
    transpose_out<<<1024, 256, 0, stream>>>(ut, out);
  } else {
    fused_kernel<false><<<NKH, 512, 0, stream>>>(u, a, b, c, out);
  }
}

// Round 5
// 171.600 us; speedup vs baseline: 1.5132x; 1.5132x over previous
//
#include <hip/hip_runtime.h>

// CompanionSSM, one launch: one block (8 waves, 512 thr) per head.
// De-lockstepped round-0 structure: wave 0 is a dedicated serial scanner,
// waves 1-7 produce R-slots and consume S-slots, overlapped via parity-
// disjoint double buffers with ONE barrier per quarter:
//   iter Q: wave0: scan quarter Q   (Rbuf[Q&1] -> Sbuf[Q&1])
//           waves1-7: PhaseC(Q-1)   (Sbuf[(Q-1)&1] + UB regs -> stores)
//                     PhaseA(Q+1)   (loads -> UB regs, R=V@U -> Rbuf[(Q+1)&1])
// Prep: chains without in-loop reductions + deferred dot products (r1/r2
// verified); V/W/ToepK frag-major in LDS (r3 verified layout, 1 head);
// T frags in wave-0 registers. IO/column math = round-0 verbatim.
// LDS: Rbuf 2x32KB (prep G aliases buf0) + Sbuf 2x32KB + frags 24KB + phi/kv.

#define NKH 256
#define KD  64
#define SL  4096
#define DM  1024

typedef __attribute__((ext_vector_type(8))) short short8;
typedef __attribute__((ext_vector_type(4))) float floatx4;

#define RBUF_OFF  0
#define SBUF_OFF  65536
#define FV_OFF    131072
#define FW_OFF    139264
#define FK_OFF    147456
#define PHI_OFF   155648
#define KV_OFF    156160
#define LDS_TOTAL 156416

static __device__ __forceinline__ unsigned pack_bf16(float a, float b) {
  union { float f; unsigned u; } ua, ub;
  ua.f = a; ub.f = b;
  return __builtin_amdgcn_perm(ub.u + 0x8000u, ua.u + 0x8000u, 0x07060302u);
}
static __device__ __forceinline__ unsigned short f2bfru(float x) {
  union { float f; unsigned u; } v; v.f = x;
  return (unsigned short)((v.u + 0x8000u) >> 16);
}
static __device__ __forceinline__ float bflo(unsigned d) {
  union { unsigned u; float f; } v; v.u = d << 16; return v.f;
}
static __device__ __forceinline__ float bfhi(unsigned d) {
  union { unsigned u; float f; } v; v.u = d & 0xffff0000u; return v.f;
}
static __device__ __forceinline__ float bf2f(unsigned short s) {
  union { unsigned u; float f; } v; v.u = ((unsigned)s) << 16; return v.f;
}
static __device__ __forceinline__ float wredsum(float x) {
#pragma unroll
  for (int off = 32; off; off >>= 1) x += __shfl_xor(x, off, 64);
  return x;
}
// frag-major 16B-group byte offset for 64x64 bf16: element (row, colg..colg+7)
static __device__ __forceinline__ int fmoff(int row, int colg) {
  return ((((row >> 4) * 2 + (colg >> 5)) * 64 + ((colg >> 3) & 3) * 16 + (row & 15)) << 4);
}

// -------- producer: Phase A for quarter QN -> Rbuf[QN&1], UB kept --------
#define PRODUCE(QN, UBARR) do { \
  char* rbuf_ = lds + RBUF_OFF + ((QN) & 1) * 32768; \
  _Pragma("unroll") \
  for (int ci = 0; ci < 3; ++ci) { \
    const int lq_ = myw + 7 * ci; \
    if (lq_ < 16) { \
      const int qg_ = (QN) * 16 + lq_; \
      float ur_[16]; \
      _Pragma("unroll") \
      for (int j_ = 0; j_ < 8; ++j_) { \
        ur_[j_]     = up[(size_t)(qg_*64 +      quad*8 + j_) * DM]; \
        ur_[8 + j_] = up[(size_t)(qg_*64 + 32 + quad*8 + j_) * DM]; \
      } \
      union { short8 v; unsigned s4[4]; } b2_, b3_; \
      _Pragma("unroll") \
      for (int jj_ = 0; jj_ < 4; ++jj_) { \
        b2_.s4[jj_] = pack_bf16(ur_[2*jj_],     ur_[2*jj_ + 1]); \
        b3_.s4[jj_] = pack_bf16(ur_[8 + 2*jj_], ur_[8 + 2*jj_ + 1]); \
      } \
      UBARR[ci][0] = b2_.v; UBARR[ci][1] = b3_.v; \
      char* slot_ = rbuf_ + lq_ * 2048; \
      _Pragma("unroll") \
      for (int rt_ = 0; rt_ < 4; ++rt_) { \
        const short8 v0_ = *(const short8*)(lds + FV_OFF + (((rt_*2 + 0)*64 + lane) << 4)); \
        const short8 v1_ = *(const short8*)(lds + FV_OFF + (((rt_*2 + 1)*64 + lane) << 4)); \
        floatx4 r_ = {0.f, 0.f, 0.f, 0.f}; \
        r_ = __builtin_amdgcn_mfma_f32_16x16x32_bf16(v0_, UBARR[ci][0], r_, 0,0,0); \
        r_ = __builtin_amdgcn_mfma_f32_16x16x32_bf16(v1_, UBARR[ci][1], r_, 0,0,0); \
        uint2 pk_; pk_.x = pack_bf16(r_[0], r_[1]); pk_.y = pack_bf16(r_[2], r_[3]); \
        *(uint2*)(slot_ + rt_*512 + lane*8) = pk_; \
      } \
    } \
  } \
} while (0)

// -------- consumer: Phase C for quarter QC from Sbuf[QC&1] + UB regs --------
#define CONSUME(QC, UBARR) do { \
  char* sbuf_ = lds + SBUF_OFF + ((QC) & 1) * 32768; \
  _Pragma("unroll") \
  for (int ci = 0; ci < 3; ++ci) { \
    const int lq_ = myw + 7 * ci; \
    if (lq_ < 16) { \
      const int qg_ = (QC) * 16 + lq_; \
      char* ss_ = sbuf_ + lq_ * 2048; \
      const short8 S0_ = *(const short8*)(ss_ + lane*16); \
      const short8 S1_ = *(const short8*)(ss_ + 1024 + lane*16); \
      _Pragma("unroll") \
      for (int rt_ = 0; rt_ < 4; ++rt_) { \
        const short8 k0_ = *(const short8*)(lds + FK_OFF + (((rt_*2 + 0)*64 + lane) << 4)); \
        const short8 k1_ = *(const short8*)(lds + FK_OFF + (((rt_*2 + 1)*64 + lane) << 4)); \
        const short8 w0_ = *(const short8*)(lds + FW_OFF + (((rt_*2 + 0)*64 + lane) << 4)); \
        const short8 w1_ = *(const short8*)(lds + FW_OFF + (((rt_*2 + 1)*64 + lane) << 4)); \
        floatx4 ty_ = {0.f, 0.f, 0.f, 0.f}; \
        ty_ = __builtin_amdgcn_mfma_f32_16x16x32_bf16(k0_, UBARR[ci][0], ty_, 0,0,0); \
        ty_ = __builtin_amdgcn_mfma_f32_16x16x32_bf16(k1_, UBARR[ci][1], ty_, 0,0,0); \
        ty_ = __builtin_amdgcn_mfma_f32_16x16x32_bf16(w0_, S0_,          ty_, 0,0,0); \
        ty_ = __builtin_amdgcn_mfma_f32_16x16x32_bf16(w1_, S1_,          ty_, 0,0,0); \
        const size_t rbase_ = (size_t)(qg_*64 + 16*rt_ + 4*quad); \
        _Pragma("unroll") \
        for (int r_ = 0; r_ < 4; ++r_) op[(rbase_ + r_) * DM] = ty_[r_]; \
      } \
    } \
  } \
} while (0)

// -------- scanner (wave 0): quarter QN: Rbuf[QN&1] -> Sbuf[QN&1] --------
#define SCANQ(QN) do { \
  char* rbuf_ = lds + RBUF_OFF + ((QN) & 1) * 32768; \
  char* sbuf_ = lds + SBUF_OFF + ((QN) & 1) * 32768; \
  _Pragma("unroll 1") \
  for (int lq_ = 0; lq_ < 16; ++lq_) { \
    char* sp_ = rbuf_ + lq_ * 2048; \
    uint2 rb_[4]; \
    _Pragma("unroll") \
    for (int rt_ = 0; rt_ < 4; ++rt_) rb_[rt_] = *(const uint2*)(sp_ + rt_*512 + lane*8); \
    *(short8*)(sbuf_ + lq_*2048 + lane*16)        = B0; \
    *(short8*)(sbuf_ + lq_*2048 + 1024 + lane*16) = B1; \
    floatx4 acc_[4]; \
    _Pragma("unroll") \
    for (int rt_ = 0; rt_ < 4; ++rt_) { \
      floatx4 cs_; \
      cs_[0] = bflo(rb_[rt_].x); cs_[1] = bfhi(rb_[rt_].x); \
      cs_[2] = bflo(rb_[rt_].y); cs_[3] = bfhi(rb_[rt_].y); \
      floatx4 a0_ = __builtin_amdgcn_mfma_f32_16x16x32_bf16(At[rt_][0], B0, cs_, 0,0,0); \
      acc_[rt_]  = __builtin_amdgcn_mfma_f32_16x16x32_bf16(At[rt_][1], B1, a0_, 0,0,0); \
    } \
    unsigned pk_[4][2]; \
    _Pragma("unroll") \
    for (int rt_ = 0; rt_ < 4; ++rt_) { \
      pk_[rt_][0] = pack_bf16(acc_[rt_][0], acc_[rt_][1]); \
      pk_[rt_][1] = pack_bf16(acc_[rt_][2], acc_[rt_][3]); \
    } \
    union { short8 v; unsigned uu[4]; } nb0_, nb1_; \
    unsigned xa_, xb_; \
    xa_ = __shfl(pk_[0][0], srcA, 64); xb_ = __shfl(pk_[1][0], srcA, 64); nb0_.uu[0] = hi ? xb_ : xa_; \
    xa_ = __shfl(pk_[0][1], srcA, 64); xb_ = __shfl(pk_[1][1], srcA, 64); nb0_.uu[1] = hi ? xb_ : xa_; \
    xa_ = __shfl(pk_[0][0], srcB, 64); xb_ = __shfl(pk_[1][0], srcB, 64); nb0_.uu[2] = hi ? xb_ : xa_; \
    xa_ = __shfl(pk_[0][1], srcB, 64); xb_ = __shfl(pk_[1][1], srcB, 64); nb0_.uu[3] = hi ? xb_ : xa_; \
    xa_ = __shfl(pk_[2][0], srcA, 64); xb_ = __shfl(pk_[3][0], srcA, 64); nb1_.uu[0] = hi ? xb_ : xa_; \
    xa_ = __shfl(pk_[2][1], srcA, 64); xb_ = __shfl(pk_[3][1], srcA, 64); nb1_.uu[1] = hi ? xb_ : xa_; \
    xa_ = __shfl(pk_[2][0], srcB, 64); xb_ = __shfl(pk_[3][0], srcB, 64); nb1_.uu[2] = hi ? xb_ : xa_; \
    xa_ = __shfl(pk_[2][1], srcB, 64); xb_ = __shfl(pk_[3][1], srcB, 64); nb1_.uu[3] = hi ? xb_ : xa_; \
    B0 = nb0_.v; B1 = nb1_.v; \
  } \
} while (0)

__global__ __launch_bounds__(512, 1) void fused_kernel(
    const float* __restrict__ u, const float* __restrict__ ga,
    const float* __restrict__ gb, const float* __restrict__ gc,
    float* __restrict__ out)
{
  __shared__ __align__(16) char lds[LDS_TOTAL];
  unsigned short* G = (unsigned short*)lds;     // prep: rows 64..127, stride 128
  float* phi = (float*)(lds + PHI_OFF);
  float* kv  = (float*)(lds + KV_OFF);

  const int i = blockIdx.x;
  const int h = 8 * (i & 31) + (i >> 5);        // heads 8g..8g+7 -> same XCD
  const int t = threadIdx.x;
  const int w = t >> 6, lane = t & 63;
  const int n16 = lane & 15, quad = lane >> 4;
  const int myw = w - 1;                        // producer index (w>=1)

  // ---------------- prep chains (no in-loop reductions) ----------------
  if (w < 2) {
    const float av = ga[h*KD + lane];
    const float an = av / wredsum(fabsf(av));   // mean(|rowsum|) >> eps
    if (w == 1) {
      phi[lane] = gc[h*KD + lane];              // phi[0..63] = c
      float g = an;                             // g_64 = A^64 e0 = a_n
      for (int p = 64; p < 128; ++p) {
        G[(64 + lane)*128 + (p - 64)] = f2bfru(g);   // T col m = g_{64+m}
        const float top = __shfl(g, 63, 64);
        const float gm1 = __shfl_up(g, 1, 64);
        g = (lane > 0 ? gm1 : 0.0f) + an * top;
      }
    } else {
      float v = gb[h*KD + lane];                // v_j = A^j b
      for (int j = 0; j < KD; ++j) {
        G[(64 + lane)*128 + 64 + (63 - j)] = f2bfru(v);  // V col m = v_{63-m}
        const float top = __shfl(v, 63, 64);
        const float vm1 = __shfl_up(v, 1, 64);
        v = (lane > 0 ? vm1 : 0.0f) + an * top;
      }
    }
  }
  __syncthreads();

  // ------- deferred dot products: phi[64..127] and kv[0..63] -------
  if (t < 128) {
    float acc = 0.f;
    for (int n = 0; n < 64; ++n)
      acc += phi[n] * bf2f(G[(64 + n)*128 + t]);
    if (t < 64) phi[64 + t] = acc;      // phi[p] = c . g_p
    else        kv[127 - t] = acc;      // kv[j] = c . v_j
  }
  __syncthreads();

  // ---------------- frag-major fills: V copy, W/K direct; wave0 At --------
  {
    const int f = t >> 6, l = t & 63;           // V: one 16B group per thread
    const int rt = f >> 1, kt = f & 1;
    const int ln = l & 15, lq2 = l >> 4;
    *(uint4*)(lds + FV_OFF + ((f*64 + l) << 4)) =
        *(const uint4*)(G + (64 + 16*rt + ln)*128 + 64 + 32*kt + 8*lq2);
  }
  {
    const int cgi = t >> 6, row = t & 63;       // W/K: 64 rows x 8 colgroups
    const int colg = cgi * 8;
    union { short8 v; unsigned short us[8]; } wb, kb;
#pragma unroll
    for (int jj = 0; jj < 8; ++jj) {
      wb.us[jj] = f2bfru(phi[row + 1 + colg + jj]);
      const int m = colg + jj;
      kb.us[jj] = (m <= row) ? f2bfru(kv[row - m]) : (unsigned short)0;
    }
    *(short8*)(lds + FW_OFF + fmoff(row, colg)) = wb.v;
    *(short8*)(lds + FK_OFF + fmoff(row, colg)) = kb.v;
  }
  short8 At[4][2];
  if (w == 0) {
#pragma unroll
    for (int rt = 0; rt < 4; ++rt)
#pragma unroll
      for (int kt = 0; kt < 2; ++kt)
        At[rt][kt] = *(const short8*)(G + (64 + 16*rt + n16)*128 + 32*kt + quad*8);
  }
  __syncthreads();   // G (aliasing Rbuf0) dead -> buffers usable

  // ---------------- main: overlapped quarters ----------------
  const size_t cs = (size_t)(n16 >> 2) * ((size_t)SL * DM) + 4*h + (n16 & 3);
  const float* up = u + cs;
  float*       op = out + cs;
  const int srcA = n16 + 16*((2*quad) & 3);
  const int srcB = n16 + 16*((2*quad + 1) & 3);
  const bool hi = (quad >= 2);
  const short8 Z8 = {0,0,0,0,0,0,0,0};
  short8 B0 = Z8, B1 = Z8;                // scan carry (wave 0)
  short8 UBa[3][2], UBb[3][2];            // producer U frags, 2 quarters live

  // prologue: produce quarter 0
  if (w != 0) PRODUCE(0, UBa);
  __syncthreads();

  // iter 0: scan Q0 || produce Q1
  if (w == 0) SCANQ(0); else PRODUCE(1, UBb);
  __syncthreads();
  // iter 1: scan Q1 || consume Q0, produce Q2
  if (w == 0) SCANQ(1); else { CONSUME(0, UBa); PRODUCE(2, UBa); }
  __syncthreads();
  // iter 2: scan Q2 || consume Q1, produce Q3
  if (w == 0) SCANQ(2); else { CONSUME(1, UBb); PRODUCE(3, UBb); }
  __syncthreads();
  // iter 3: scan Q3 || consume Q2
  if (w == 0) SCANQ(3); else CONSUME(2, UBa);
  __syncthreads();
  // tail: consume Q3
  if (w != 0) CONSUME(3, UBb);
}

// ---------------------------------------------------------------- launch --
extern "C" void kernel_launch(void* const* d_in, const int* in_sizes, int n_in,
                              void* d_out, int out_size, void* d_ws, size_t ws_size,
                              hipStream_t stream)
{
  const float* u = (const float*)d_in[0];
  const float* a = (const float*)d_in[1];
  const float* b = (const float*)d_in[2];
  const float* c = (const float*)d_in[3];
  float* out = (float*)d_out;
  (void)d_ws; (void)ws_size; (void)in_sizes; (void)n_in; (void)out_size;

  fused_kernel<<<NKH, 512, 0, stream>>>(u, a, b, c, out);
}